// Round 1
// baseline (3073.086 us; speedup 1.0000x reference)
//
#include <hip/hip_runtime.h>
#include <cstddef>

// ---------------- degree / norm ----------------
__global__ void k_degree(const int* __restrict__ dst, int* __restrict__ cnt, int E) {
    int e = blockIdx.x * 256 + threadIdx.x;
    if (e < E) atomicAdd(&cnt[dst[e]], 1);
}

__global__ void k_dinv(const int* __restrict__ cnt, float* __restrict__ dinv, int N) {
    int i = blockIdx.x * 256 + threadIdx.x;
    if (i < N) dinv[i] = rsqrtf((float)cnt[i] + 1.0f);
}

// ---------------- GEMM: Y[N,128] = X[N,128] @ W[128,128] ----------------
// 32 rows/block, W fully staged in LDS (64KB), X tile 16KB. Each thread: 4x4 outputs.
__global__ __launch_bounds__(256) void k_gemm128(const float* __restrict__ X,
                                                 const float* __restrict__ W,
                                                 float* __restrict__ Y, int N) {
    __shared__ float Ws[128 * 128];
    __shared__ float Xs[32][128];
    int tid = threadIdx.x;

    const float4* W4 = (const float4*)W;
    float4* Ws4 = (float4*)Ws;
    #pragma unroll
    for (int i = 0; i < 16; ++i) Ws4[tid + i * 256] = W4[tid + i * 256];  // 4096 float4

    int row0 = blockIdx.x * 32;
    int nrow = min(32, N - row0);
    const float4* X4 = (const float4*)(X + (size_t)row0 * 128);
    float4* Xs4 = (float4*)&Xs[0][0];
    for (int i = tid; i < nrow * 32; i += 256) Xs4[i] = X4[i];
    __syncthreads();

    int rg = tid >> 5;   // 0..7 -> 4 rows each
    int cg = tid & 31;   // 0..31 -> 4 cols each
    int r0 = rg * 4, c0 = cg * 4;
    float acc[4][4] = {};
    for (int k = 0; k < 128; ++k) {
        float4 wv = *(const float4*)&Ws[k * 128 + c0];
        #pragma unroll
        for (int i = 0; i < 4; ++i) {
            float xv = Xs[r0 + i][k];
            acc[i][0] += xv * wv.x;
            acc[i][1] += xv * wv.y;
            acc[i][2] += xv * wv.z;
            acc[i][3] += xv * wv.w;
        }
    }
    #pragma unroll
    for (int i = 0; i < 4; ++i) {
        int r = row0 + r0 + i;
        if (r < N) {
            float4 o = make_float4(acc[i][0], acc[i][1], acc[i][2], acc[i][3]);
            *(float4*)&Y[(size_t)r * 128 + c0] = o;
        }
    }
}

// ---------------- edge aggregation (atomics) ----------------
// 32 threads per edge, each handles one float4 of the 128-float row.
__global__ void k_aggregate(const float* __restrict__ T, const int* __restrict__ src,
                            const int* __restrict__ dst, const float* __restrict__ dinv,
                            float* __restrict__ AGG, int E) {
    int t = blockIdx.x * 256 + threadIdx.x;
    int e = t >> 5;
    if (e >= E) return;
    int f = (t & 31) << 2;
    int s = src[e], d = dst[e];
    float nrm = dinv[s] * dinv[d];
    float4 v = *(const float4*)&T[(size_t)s * 128 + f];
    float* o = &AGG[(size_t)d * 128 + f];
    atomicAdd(o + 0, v.x * nrm);
    atomicAdd(o + 1, v.y * nrm);
    atomicAdd(o + 2, v.z * nrm);
    atomicAdd(o + 3, v.w * nrm);
}

// ---------------- epilogue: out = relu(AGG + T*dinv^2 + b) ----------------
__global__ void k_finish(const float* __restrict__ AGG, const float* __restrict__ T,
                         const float* __restrict__ dinv, const float* __restrict__ b,
                         float* __restrict__ OUT, int N) {
    int i = blockIdx.x * 256 + threadIdx.x;
    if (i >= N * 128) return;
    int r = i >> 7, c = i & 127;
    float dn = dinv[r];
    float v = AGG[i] + T[i] * dn * dn + b[c];
    OUT[i] = fmaxf(v, 0.0f);
}

// ---------------- pooling (atomics) ----------------
__global__ void k_pool(const float* __restrict__ H, const int* __restrict__ batch,
                       float* __restrict__ pooled, int* __restrict__ pcnt, int N) {
    int t = blockIdx.x * 256 + threadIdx.x;
    int n = t >> 5;
    if (n >= N) return;
    int f = (t & 31) << 2;
    int g = batch[n];
    float4 v = *(const float4*)&H[(size_t)n * 128 + f];
    float* o = &pooled[g * 128 + f];
    atomicAdd(o + 0, v.x);
    atomicAdd(o + 1, v.y);
    atomicAdd(o + 2, v.z);
    atomicAdd(o + 3, v.w);
    if (f == 0) atomicAdd(&pcnt[g], 1);
}

// ---------------- fc1: Z[128,64] = relu(pooled/cnt @ W + b) ----------------
__global__ void k_fc1(const float* __restrict__ pooled, const int* __restrict__ pcnt,
                      const float* __restrict__ W, const float* __restrict__ b,
                      float* __restrict__ Z) {
    int g = blockIdx.x, c = threadIdx.x;  // 128 blocks x 64 threads
    float inv = 1.0f / fmaxf((float)pcnt[g], 1.0f);
    float acc = b[c];
    for (int k = 0; k < 128; ++k)
        acc += pooled[g * 128 + k] * inv * W[k * 64 + c];
    Z[g * 64 + c] = fmaxf(acc, 0.0f);
}

// ---------------- BN (training stats) + final linear ----------------
__global__ void k_bn_out(const float* __restrict__ Z, const float* __restrict__ gamma,
                         const float* __restrict__ beta, const float* __restrict__ w3,
                         const float* __restrict__ b3, float* __restrict__ out) {
    __shared__ float mu[64], rs[64], gw[64], bw[64];
    int t = threadIdx.x;  // 256 threads, 1 block
    if (t < 64) {
        float s = 0.f, ss = 0.f;
        for (int g = 0; g < 128; ++g) {
            float v = Z[g * 64 + t];
            s += v; ss += v * v;
        }
        float m = s * (1.0f / 128.0f);
        float var = ss * (1.0f / 128.0f) - m * m;
        mu[t] = m;
        rs[t] = rsqrtf(var + 1e-5f);
        gw[t] = gamma[t];
        bw[t] = beta[t];
    }
    __syncthreads();
    if (t < 128) {
        float acc = b3[0];
        for (int c = 0; c < 64; ++c)
            acc += ((Z[t * 64 + c] - mu[c]) * rs[c] * gw[c] + bw[c]) * w3[c];
        out[t] = acc;
    }
}

extern "C" void kernel_launch(void* const* d_in, const int* in_sizes, int n_in,
                              void* d_out, int out_size, void* d_ws, size_t ws_size,
                              hipStream_t stream) {
    const float* x    = (const float*)d_in[0];
    const int* eidx   = (const int*)d_in[1];
    const int* batch  = (const int*)d_in[2];
    const float* W1   = (const float*)d_in[3];
    const float* b1   = (const float*)d_in[4];
    const float* W2   = (const float*)d_in[5];
    const float* b2   = (const float*)d_in[6];
    const float* fcW1 = (const float*)d_in[7];
    const float* fcb1 = (const float*)d_in[8];
    const float* gamma= (const float*)d_in[9];
    const float* beta = (const float*)d_in[10];
    const float* fcW3 = (const float*)d_in[11];
    const float* fcb3 = (const float*)d_in[12];
    float* out = (float*)d_out;

    const int N = in_sizes[0] / 128;
    const int E = in_sizes[1] / 2;
    const int* src = eidx;
    const int* dst = eidx + E;

    // workspace layout
    char* ws = (char*)d_ws;
    float* bufA = (float*)ws;                          // N*128
    float* bufB = bufA + (size_t)N * 128;              // N*128
    int*   cnt  = (int*)(bufB + (size_t)N * 128);      // N
    float* dinv = (float*)(cnt + N);                   // N
    float* pooled = dinv + N;                          // 128*128
    int*   pcnt = (int*)(pooled + 128 * 128);          // 128
    float* Z    = (float*)(pcnt + 128);                // 128*64

    const int TB = 256;
    int gemm_blocks = (N + 31) / 32;
    int agg_blocks  = (E * 32 + TB - 1) / TB;
    int fin_blocks  = (N * 128 + TB - 1) / TB;
    int pool_blocks = (N * 32 + TB - 1) / TB;

    // degree + dinv
    hipMemsetAsync(cnt, 0, (size_t)N * sizeof(int), stream);
    k_degree<<<(E + TB - 1) / TB, TB, 0, stream>>>(dst, cnt, E);
    k_dinv<<<(N + TB - 1) / TB, TB, 0, stream>>>(cnt, dinv, N);

    // layer 1: bufA = x@W1 ; bufB = scatter ; h1 = relu(...) -> bufA
    k_gemm128<<<gemm_blocks, TB, 0, stream>>>(x, W1, bufA, N);
    hipMemsetAsync(bufB, 0, (size_t)N * 128 * sizeof(float), stream);
    k_aggregate<<<agg_blocks, TB, 0, stream>>>(bufA, src, dst, dinv, bufB, E);
    k_finish<<<fin_blocks, TB, 0, stream>>>(bufB, bufA, dinv, b1, bufA, N);

    // layer 2: bufB = h1@W2 ; bufA = scatter ; h2 = relu(...) -> bufA
    k_gemm128<<<gemm_blocks, TB, 0, stream>>>(bufA, W2, bufB, N);
    hipMemsetAsync(bufA, 0, (size_t)N * 128 * sizeof(float), stream);
    k_aggregate<<<agg_blocks, TB, 0, stream>>>(bufB, src, dst, dinv, bufA, E);
    k_finish<<<fin_blocks, TB, 0, stream>>>(bufA, bufB, dinv, b2, bufA, N);

    // pooling
    hipMemsetAsync(pooled, 0, (128 * 128) * sizeof(float) + 128 * sizeof(int), stream);
    k_pool<<<pool_blocks, TB, 0, stream>>>(bufA, batch, pooled, pcnt, N);

    // head
    k_fc1<<<128, 64, 0, stream>>>(pooled, pcnt, fcW1, fcb1, Z);
    k_bn_out<<<1, 256, 0, stream>>>(Z, gamma, beta, fcW3, fcb3, out);
}

// Round 2
// 401.355 us; speedup vs baseline: 7.6568x; 7.6568x over previous
//
#include <hip/hip_runtime.h>
#include <cstddef>

// ---------------- degree / norm ----------------
__global__ void k_degree(const int* __restrict__ dst, int* __restrict__ cnt, int E) {
    int e = blockIdx.x * 256 + threadIdx.x;
    if (e < E) atomicAdd(&cnt[dst[e]], 1);
}

__global__ void k_dinv(const int* __restrict__ cnt, float* __restrict__ dinv, int N) {
    int i = blockIdx.x * 256 + threadIdx.x;
    if (i < N) dinv[i] = rsqrtf((float)cnt[i] + 1.0f);
}

// ---------------- exclusive scan of cnt -> rowptr (3 passes) ----------------
__global__ void k_scan1(const int* __restrict__ cnt, int* __restrict__ rowptr,
                        int* __restrict__ bsum, int N) {
    __shared__ int s[256];
    int i = blockIdx.x * 256 + threadIdx.x;
    int v = (i < N) ? cnt[i] : 0;
    s[threadIdx.x] = v;
    __syncthreads();
    for (int off = 1; off < 256; off <<= 1) {
        int t = (threadIdx.x >= off) ? s[threadIdx.x - off] : 0;
        __syncthreads();
        s[threadIdx.x] += t;
        __syncthreads();
    }
    if (i < N) rowptr[i] = s[threadIdx.x];          // inclusive, per-block
    if (threadIdx.x == 255) bsum[blockIdx.x] = s[255];
}

__global__ void k_scan2(int* __restrict__ bsum, int nb) {
    __shared__ int s[256];
    __shared__ int carry;
    if (threadIdx.x == 0) carry = 0;
    __syncthreads();
    for (int base = 0; base < nb; base += 256) {
        int i = base + threadIdx.x;
        int v = (i < nb) ? bsum[i] : 0;
        s[threadIdx.x] = v;
        __syncthreads();
        for (int off = 1; off < 256; off <<= 1) {
            int t = (threadIdx.x >= off) ? s[threadIdx.x - off] : 0;
            __syncthreads();
            s[threadIdx.x] += t;
            __syncthreads();
        }
        if (i < nb) bsum[i] = s[threadIdx.x] + carry;
        __syncthreads();
        if (threadIdx.x == 0) carry += s[255];
        __syncthreads();
    }
}

__global__ void k_scan3(int* __restrict__ rowptr, const int* __restrict__ cnt,
                        const int* __restrict__ bsum, int N) {
    int i = blockIdx.x * 256 + threadIdx.x;
    if (i >= N) return;
    int boff = (blockIdx.x > 0) ? bsum[blockIdx.x - 1] : 0;
    rowptr[i] = rowptr[i] - cnt[i] + boff;          // exclusive scan
}

// ---------------- scatter edges into CSR by dst ----------------
__global__ void k_scatter(const int* __restrict__ src, const int* __restrict__ dst,
                          const int* __restrict__ rowptr, int* __restrict__ fill,
                          int* __restrict__ csr_src, int E) {
    int e = blockIdx.x * 256 + threadIdx.x;
    if (e >= E) return;
    int d = dst[e];
    int pos = rowptr[d] + atomicAdd(&fill[d], 1);
    csr_src[pos] = src[e];
}

// ---------------- GEMM: Y[N,128] = X[N,128] @ W[128,128] ----------------
__global__ __launch_bounds__(256) void k_gemm128(const float* __restrict__ X,
                                                 const float* __restrict__ W,
                                                 float* __restrict__ Y, int N) {
    __shared__ float Ws[128 * 128];
    __shared__ float Xs[32][128];
    int tid = threadIdx.x;

    const float4* W4 = (const float4*)W;
    float4* Ws4 = (float4*)Ws;
    #pragma unroll
    for (int i = 0; i < 16; ++i) Ws4[tid + i * 256] = W4[tid + i * 256];

    int row0 = blockIdx.x * 32;
    int nrow = min(32, N - row0);
    const float4* X4 = (const float4*)(X + (size_t)row0 * 128);
    float4* Xs4 = (float4*)&Xs[0][0];
    for (int i = tid; i < nrow * 32; i += 256) Xs4[i] = X4[i];
    __syncthreads();

    int rg = tid >> 5;
    int cg = tid & 31;
    int r0 = rg * 4, c0 = cg * 4;
    float acc[4][4] = {};
    for (int k = 0; k < 128; ++k) {
        float4 wv = *(const float4*)&Ws[k * 128 + c0];
        #pragma unroll
        for (int i = 0; i < 4; ++i) {
            float xv = Xs[r0 + i][k];
            acc[i][0] += xv * wv.x;
            acc[i][1] += xv * wv.y;
            acc[i][2] += xv * wv.z;
            acc[i][3] += xv * wv.w;
        }
    }
    #pragma unroll
    for (int i = 0; i < 4; ++i) {
        int r = row0 + r0 + i;
        if (r < N) {
            float4 o = make_float4(acc[i][0], acc[i][1], acc[i][2], acc[i][3]);
            *(float4*)&Y[(size_t)r * 128 + c0] = o;
        }
    }
}

// ---------------- fused pull aggregation + self-loop + bias + relu ----------
// one wave per node; lane owns float2 of the 128-wide row.
__global__ __launch_bounds__(256) void k_gcn_agg(const float* __restrict__ T,
                                                 const int* __restrict__ csr_src,
                                                 const int* __restrict__ rowptr,
                                                 const int* __restrict__ cnt,
                                                 const float* __restrict__ dinv,
                                                 const float* __restrict__ b,
                                                 float* __restrict__ OUT, int N) {
    int node = blockIdx.x * 4 + (threadIdx.x >> 6);
    if (node >= N) return;
    int lane = threadIdx.x & 63;
    int start = rowptr[node];
    int len = cnt[node];
    float dn = dinv[node];

    float2 self = *(const float2*)(T + (size_t)node * 128 + lane * 2);
    float accx = self.x * dn * dn;
    float accy = self.y * dn * dn;

    int j = 0;
    for (; j + 3 < len; j += 4) {
        int s0 = csr_src[start + j + 0];
        int s1 = csr_src[start + j + 1];
        int s2 = csr_src[start + j + 2];
        int s3 = csr_src[start + j + 3];
        float w0 = dinv[s0] * dn;
        float w1 = dinv[s1] * dn;
        float w2 = dinv[s2] * dn;
        float w3 = dinv[s3] * dn;
        float2 v0 = *(const float2*)(T + (size_t)s0 * 128 + lane * 2);
        float2 v1 = *(const float2*)(T + (size_t)s1 * 128 + lane * 2);
        float2 v2 = *(const float2*)(T + (size_t)s2 * 128 + lane * 2);
        float2 v3 = *(const float2*)(T + (size_t)s3 * 128 + lane * 2);
        accx += w0 * v0.x + w1 * v1.x + w2 * v2.x + w3 * v3.x;
        accy += w0 * v0.y + w1 * v1.y + w2 * v2.y + w3 * v3.y;
    }
    for (; j < len; ++j) {
        int s = csr_src[start + j];
        float w = dinv[s] * dn;
        float2 v = *(const float2*)(T + (size_t)s * 128 + lane * 2);
        accx += w * v.x;
        accy += w * v.y;
    }

    accx = fmaxf(accx + b[lane * 2 + 0], 0.0f);
    accy = fmaxf(accy + b[lane * 2 + 1], 0.0f);
    float2 o = make_float2(accx, accy);
    *(float2*)(OUT + (size_t)node * 128 + lane * 2) = o;
}

// ---------------- pooling: one block per graph, batch is sorted -------------
__global__ __launch_bounds__(128) void k_pool2(const float* __restrict__ H,
                                               const int* __restrict__ batch,
                                               float* __restrict__ pooled, int N) {
    int g = blockIdx.x;
    int t = threadIdx.x;  // 128 threads = 128 feature cols
    // binary search [s,e) of graph g in sorted batch
    int lo = 0, hi = N;
    while (lo < hi) { int m = (lo + hi) >> 1; if (batch[m] < g) lo = m + 1; else hi = m; }
    int s = lo;
    lo = s; hi = N;
    while (lo < hi) { int m = (lo + hi) >> 1; if (batch[m] <= g) lo = m + 1; else hi = m; }
    int e = lo;
    float acc = 0.0f;
    for (int n = s; n < e; ++n) acc += H[(size_t)n * 128 + t];
    pooled[g * 128 + t] = acc / fmaxf((float)(e - s), 1.0f);
}

// ---------------- fc1: Z[128,64] = relu(pooled @ W + b) ----------------
__global__ void k_fc1(const float* __restrict__ pooled, const float* __restrict__ W,
                      const float* __restrict__ b, float* __restrict__ Z) {
    int g = blockIdx.x, c = threadIdx.x;  // 128 blocks x 64 threads
    float acc = b[c];
    for (int k = 0; k < 128; ++k)
        acc += pooled[g * 128 + k] * W[k * 64 + c];
    Z[g * 64 + c] = fmaxf(acc, 0.0f);
}

// ---------------- BN (training stats) + final linear ----------------
__global__ void k_bn_out(const float* __restrict__ Z, const float* __restrict__ gamma,
                         const float* __restrict__ beta, const float* __restrict__ w3,
                         const float* __restrict__ b3, float* __restrict__ out) {
    __shared__ float mu[64], rs[64], gw[64], bw[64];
    int t = threadIdx.x;
    if (t < 64) {
        float s = 0.f, ss = 0.f;
        for (int g = 0; g < 128; ++g) {
            float v = Z[g * 64 + t];
            s += v; ss += v * v;
        }
        float m = s * (1.0f / 128.0f);
        float var = ss * (1.0f / 128.0f) - m * m;
        mu[t] = m;
        rs[t] = rsqrtf(var + 1e-5f);
        gw[t] = gamma[t];
        bw[t] = beta[t];
    }
    __syncthreads();
    if (t < 128) {
        float acc = b3[0];
        for (int c = 0; c < 64; ++c)
            acc += ((Z[t * 64 + c] - mu[c]) * rs[c] * gw[c] + bw[c]) * w3[c];
        out[t] = acc;
    }
}

extern "C" void kernel_launch(void* const* d_in, const int* in_sizes, int n_in,
                              void* d_out, int out_size, void* d_ws, size_t ws_size,
                              hipStream_t stream) {
    const float* x    = (const float*)d_in[0];
    const int* eidx   = (const int*)d_in[1];
    const int* batch  = (const int*)d_in[2];
    const float* W1   = (const float*)d_in[3];
    const float* b1   = (const float*)d_in[4];
    const float* W2   = (const float*)d_in[5];
    const float* b2   = (const float*)d_in[6];
    const float* fcW1 = (const float*)d_in[7];
    const float* fcb1 = (const float*)d_in[8];
    const float* gamma= (const float*)d_in[9];
    const float* beta = (const float*)d_in[10];
    const float* fcW3 = (const float*)d_in[11];
    const float* fcb3 = (const float*)d_in[12];
    float* out = (float*)d_out;

    const int N = in_sizes[0] / 128;
    const int E = in_sizes[1] / 2;
    const int* src = eidx;
    const int* dst = eidx + E;

    // workspace layout
    char* ws = (char*)d_ws;
    float* bufA   = (float*)ws;                        // N*128
    float* bufB   = bufA + (size_t)N * 128;            // N*128
    int*   cnt    = (int*)(bufB + (size_t)N * 128);    // N
    float* dinv   = (float*)(cnt + N);                 // N
    int*   rowptr = (int*)(dinv + N);                  // N
    int*   fill   = rowptr + N;                        // N
    int*   bsum   = fill + N;                          // 1024
    int*   csr_src= bsum + 1024;                       // E
    float* pooled = (float*)(csr_src + E);             // 128*128
    float* Z      = pooled + 128 * 128;                // 128*64

    const int TB = 256;
    int nblk = (N + TB - 1) / TB;
    int eblk = (E + TB - 1) / TB;
    int gemm_blocks = (N + 31) / 32;
    int agg_blocks  = (N + 3) / 4;

    hipMemsetAsync(cnt, 0, (size_t)N * sizeof(int), stream);
    hipMemsetAsync(fill, 0, (size_t)N * sizeof(int), stream);

    // CSR build
    k_degree<<<eblk, TB, 0, stream>>>(dst, cnt, E);
    k_dinv<<<nblk, TB, 0, stream>>>(cnt, dinv, N);
    k_scan1<<<nblk, TB, 0, stream>>>(cnt, rowptr, bsum, N);
    k_scan2<<<1, TB, 0, stream>>>(bsum, nblk);
    k_scan3<<<nblk, TB, 0, stream>>>(rowptr, cnt, bsum, N);
    k_scatter<<<eblk, TB, 0, stream>>>(src, dst, rowptr, fill, csr_src, E);

    // layer 1
    k_gemm128<<<gemm_blocks, TB, 0, stream>>>(x, W1, bufA, N);
    k_gcn_agg<<<agg_blocks, TB, 0, stream>>>(bufA, csr_src, rowptr, cnt, dinv, b1, bufB, N);

    // layer 2
    k_gemm128<<<gemm_blocks, TB, 0, stream>>>(bufB, W2, bufA, N);
    k_gcn_agg<<<agg_blocks, TB, 0, stream>>>(bufA, csr_src, rowptr, cnt, dinv, b2, bufB, N);

    // pool + head
    k_pool2<<<128, 128, 0, stream>>>(bufB, batch, pooled, N);
    k_fc1<<<128, 64, 0, stream>>>(pooled, fcW1, fcb1, Z);
    k_bn_out<<<1, 256, 0, stream>>>(Z, gamma, beta, fcW3, fcb3, out);
}

// Round 3
// 335.940 us; speedup vs baseline: 9.1477x; 1.1947x over previous
//
#include <hip/hip_runtime.h>
#include <cstddef>

// ---------------- degree / norm ----------------
__global__ void k_degree(const int* __restrict__ dst, int* __restrict__ cnt, int E) {
    int e = blockIdx.x * 256 + threadIdx.x;
    if (e < E) atomicAdd(&cnt[dst[e]], 1);
}

__global__ void k_dinv(const int* __restrict__ cnt, float* __restrict__ dinv, int N) {
    int i = blockIdx.x * 256 + threadIdx.x;
    if (i < N) dinv[i] = rsqrtf((float)cnt[i] + 1.0f);
}

// ---------------- exclusive scan of cnt -> rowptr (3 passes) ----------------
__global__ void k_scan1(const int* __restrict__ cnt, int* __restrict__ rowptr,
                        int* __restrict__ bsum, int N) {
    __shared__ int s[256];
    int i = blockIdx.x * 256 + threadIdx.x;
    int v = (i < N) ? cnt[i] : 0;
    s[threadIdx.x] = v;
    __syncthreads();
    for (int off = 1; off < 256; off <<= 1) {
        int t = (threadIdx.x >= off) ? s[threadIdx.x - off] : 0;
        __syncthreads();
        s[threadIdx.x] += t;
        __syncthreads();
    }
    if (i < N) rowptr[i] = s[threadIdx.x];          // inclusive, per-block
    if (threadIdx.x == 255) bsum[blockIdx.x] = s[255];
}

__global__ void k_scan2(int* __restrict__ bsum, int nb) {
    __shared__ int s[256];
    __shared__ int carry;
    if (threadIdx.x == 0) carry = 0;
    __syncthreads();
    for (int base = 0; base < nb; base += 256) {
        int i = base + threadIdx.x;
        int v = (i < nb) ? bsum[i] : 0;
        s[threadIdx.x] = v;
        __syncthreads();
        for (int off = 1; off < 256; off <<= 1) {
            int t = (threadIdx.x >= off) ? s[threadIdx.x - off] : 0;
            __syncthreads();
            s[threadIdx.x] += t;
            __syncthreads();
        }
        if (i < nb) bsum[i] = s[threadIdx.x] + carry;
        __syncthreads();
        if (threadIdx.x == 0) carry += s[255];
        __syncthreads();
    }
}

__global__ void k_scan3(int* __restrict__ rowptr, const int* __restrict__ cnt,
                        const int* __restrict__ bsum, int N) {
    int i = blockIdx.x * 256 + threadIdx.x;
    if (i >= N) return;
    int boff = (blockIdx.x > 0) ? bsum[blockIdx.x - 1] : 0;
    rowptr[i] = rowptr[i] - cnt[i] + boff;          // exclusive scan
}

// ---------------- scatter edges into CSR by dst ----------------
__global__ void k_scatter(const int* __restrict__ src, const int* __restrict__ dst,
                          const int* __restrict__ rowptr, int* __restrict__ fill,
                          int* __restrict__ csr_src, int E) {
    int e = blockIdx.x * 256 + threadIdx.x;
    if (e >= E) return;
    int d = dst[e];
    int pos = rowptr[d] + atomicAdd(&fill[d], 1);
    csr_src[pos] = src[e];
}

// ---------------- GEMM: Y[N,128] = X[N,128] @ W[128,128] ----------------
__global__ __launch_bounds__(256) void k_gemm128(const float* __restrict__ X,
                                                 const float* __restrict__ W,
                                                 float* __restrict__ Y, int N) {
    __shared__ float Ws[128 * 128];
    __shared__ float Xs[32][128];
    int tid = threadIdx.x;

    const float4* W4 = (const float4*)W;
    float4* Ws4 = (float4*)Ws;
    #pragma unroll
    for (int i = 0; i < 16; ++i) Ws4[tid + i * 256] = W4[tid + i * 256];

    int row0 = blockIdx.x * 32;
    int nrow = min(32, N - row0);
    const float4* X4 = (const float4*)(X + (size_t)row0 * 128);
    float4* Xs4 = (float4*)&Xs[0][0];
    for (int i = tid; i < nrow * 32; i += 256) Xs4[i] = X4[i];
    __syncthreads();

    int rg = tid >> 5;
    int cg = tid & 31;
    int r0 = rg * 4, c0 = cg * 4;
    float acc[4][4] = {};
    for (int k = 0; k < 128; ++k) {
        float4 wv = *(const float4*)&Ws[k * 128 + c0];
        #pragma unroll
        for (int i = 0; i < 4; ++i) {
            float xv = Xs[r0 + i][k];
            acc[i][0] += xv * wv.x;
            acc[i][1] += xv * wv.y;
            acc[i][2] += xv * wv.z;
            acc[i][3] += xv * wv.w;
        }
    }
    #pragma unroll
    for (int i = 0; i < 4; ++i) {
        int r = row0 + r0 + i;
        if (r < N) {
            float4 o = make_float4(acc[i][0], acc[i][1], acc[i][2], acc[i][3]);
            *(float4*)&Y[(size_t)r * 128 + c0] = o;
        }
    }
}

// ---------------- fused pull aggregation + self-loop + bias + relu ----------
__global__ __launch_bounds__(256) void k_gcn_agg(const float* __restrict__ T,
                                                 const int* __restrict__ csr_src,
                                                 const int* __restrict__ rowptr,
                                                 const int* __restrict__ cnt,
                                                 const float* __restrict__ dinv,
                                                 const float* __restrict__ b,
                                                 float* __restrict__ OUT, int N) {
    int node = blockIdx.x * 4 + (threadIdx.x >> 6);
    if (node >= N) return;
    int lane = threadIdx.x & 63;
    int start = rowptr[node];
    int len = cnt[node];
    float dn = dinv[node];

    float2 self = *(const float2*)(T + (size_t)node * 128 + lane * 2);
    float accx = self.x * dn * dn;
    float accy = self.y * dn * dn;

    int j = 0;
    for (; j + 3 < len; j += 4) {
        int s0 = csr_src[start + j + 0];
        int s1 = csr_src[start + j + 1];
        int s2 = csr_src[start + j + 2];
        int s3 = csr_src[start + j + 3];
        float w0 = dinv[s0] * dn;
        float w1 = dinv[s1] * dn;
        float w2 = dinv[s2] * dn;
        float w3 = dinv[s3] * dn;
        float2 v0 = *(const float2*)(T + (size_t)s0 * 128 + lane * 2);
        float2 v1 = *(const float2*)(T + (size_t)s1 * 128 + lane * 2);
        float2 v2 = *(const float2*)(T + (size_t)s2 * 128 + lane * 2);
        float2 v3 = *(const float2*)(T + (size_t)s3 * 128 + lane * 2);
        accx += w0 * v0.x + w1 * v1.x + w2 * v2.x + w3 * v3.x;
        accy += w0 * v0.y + w1 * v1.y + w2 * v2.y + w3 * v3.y;
    }
    for (; j < len; ++j) {
        int s = csr_src[start + j];
        float w = dinv[s] * dn;
        float2 v = *(const float2*)(T + (size_t)s * 128 + lane * 2);
        accx += w * v.x;
        accy += w * v.y;
    }

    accx = fmaxf(accx + b[lane * 2 + 0], 0.0f);
    accy = fmaxf(accy + b[lane * 2 + 1], 0.0f);
    float2 o = make_float2(accx, accy);
    *(float2*)(OUT + (size_t)node * 128 + lane * 2) = o;
}

// ---------------- per-graph inverse counts (batch sorted) ----------------
__global__ void k_gcount(const int* __restrict__ batch, float* __restrict__ invcnt, int N) {
    int g = threadIdx.x;  // 1 block x 128 threads
    int lo = 0, hi = N;
    while (lo < hi) { int m = (lo + hi) >> 1; if (batch[m] < g) lo = m + 1; else hi = m; }
    int s = lo;
    lo = s; hi = N;
    while (lo < hi) { int m = (lo + hi) >> 1; if (batch[m] <= g) lo = m + 1; else hi = m; }
    invcnt[g] = 1.0f / fmaxf((float)(lo - s), 1.0f);
}

// ---------------- pooling stage 2: chunked segment-sum, few atomics --------
__global__ __launch_bounds__(128) void k_pool3(const float* __restrict__ H,
                                               const int* __restrict__ batch,
                                               const float* __restrict__ invcnt,
                                               float* __restrict__ pooled, int N) {
    int t = threadIdx.x;          // feature column
    int n0 = blockIdx.x * 128;
    if (n0 >= N) return;
    int n1 = min(n0 + 128, N);
    int curg = batch[n0];
    float acc = 0.0f;
    for (int n = n0; n < n1; ++n) {
        int g = batch[n];
        if (g != curg) {
            atomicAdd(&pooled[curg * 128 + t], acc * invcnt[curg]);
            acc = 0.0f;
            curg = g;
        }
        acc += H[(size_t)n * 128 + t];
    }
    atomicAdd(&pooled[curg * 128 + t], acc * invcnt[curg]);
}

// ---------------- fc1: Z[128,64] = relu(pooled @ W + b) ----------------
__global__ void k_fc1(const float* __restrict__ pooled, const float* __restrict__ W,
                      const float* __restrict__ b, float* __restrict__ Z) {
    int g = blockIdx.x, c = threadIdx.x;  // 128 blocks x 64 threads
    float acc = b[c];
    for (int k = 0; k < 128; ++k)
        acc += pooled[g * 128 + k] * W[k * 64 + c];
    Z[g * 64 + c] = fmaxf(acc, 0.0f);
}

// ---------------- BN (training stats) + final linear ----------------
__global__ void k_bn_out(const float* __restrict__ Z, const float* __restrict__ gamma,
                         const float* __restrict__ beta, const float* __restrict__ w3,
                         const float* __restrict__ b3, float* __restrict__ out) {
    __shared__ float mu[64], rs[64], gw[64], bw[64];
    int t = threadIdx.x;
    if (t < 64) {
        float s = 0.f, ss = 0.f;
        for (int g = 0; g < 128; ++g) {
            float v = Z[g * 64 + t];
            s += v; ss += v * v;
        }
        float m = s * (1.0f / 128.0f);
        float var = ss * (1.0f / 128.0f) - m * m;
        mu[t] = m;
        rs[t] = rsqrtf(var + 1e-5f);
        gw[t] = gamma[t];
        bw[t] = beta[t];
    }
    __syncthreads();
    if (t < 128) {
        float acc = b3[0];
        for (int c = 0; c < 64; ++c)
            acc += ((Z[t * 64 + c] - mu[c]) * rs[c] * gw[c] + bw[c]) * w3[c];
        out[t] = acc;
    }
}

extern "C" void kernel_launch(void* const* d_in, const int* in_sizes, int n_in,
                              void* d_out, int out_size, void* d_ws, size_t ws_size,
                              hipStream_t stream) {
    const float* x    = (const float*)d_in[0];
    const int* eidx   = (const int*)d_in[1];
    const int* batch  = (const int*)d_in[2];
    const float* W1   = (const float*)d_in[3];
    const float* b1   = (const float*)d_in[4];
    const float* W2   = (const float*)d_in[5];
    const float* b2   = (const float*)d_in[6];
    const float* fcW1 = (const float*)d_in[7];
    const float* fcb1 = (const float*)d_in[8];
    const float* gamma= (const float*)d_in[9];
    const float* beta = (const float*)d_in[10];
    const float* fcW3 = (const float*)d_in[11];
    const float* fcb3 = (const float*)d_in[12];
    float* out = (float*)d_out;

    const int N = in_sizes[0] / 128;
    const int E = in_sizes[1] / 2;
    const int* src = eidx;
    const int* dst = eidx + E;

    // workspace layout
    char* ws = (char*)d_ws;
    float* bufA   = (float*)ws;                        // N*128
    float* bufB   = bufA + (size_t)N * 128;            // N*128
    int*   cnt    = (int*)(bufB + (size_t)N * 128);    // N
    float* dinv   = (float*)(cnt + N);                 // N
    int*   rowptr = (int*)(dinv + N);                  // N
    int*   fill   = rowptr + N;                        // N
    int*   bsum   = fill + N;                          // 1024
    int*   csr_src= bsum + 1024;                       // E
    float* pooled = (float*)(csr_src + E);             // 128*128
    float* Z      = pooled + 128 * 128;                // 128*64
    float* invcnt = Z + 128 * 64;                      // 128

    const int TB = 256;
    int nblk = (N + TB - 1) / TB;
    int eblk = (E + TB - 1) / TB;
    int gemm_blocks = (N + 31) / 32;
    int agg_blocks  = (N + 3) / 4;
    int pool_blocks = (N + 127) / 128;

    hipMemsetAsync(cnt, 0, (size_t)N * sizeof(int), stream);
    hipMemsetAsync(fill, 0, (size_t)N * sizeof(int), stream);
    hipMemsetAsync(pooled, 0, 128 * 128 * sizeof(float), stream);

    // CSR build
    k_degree<<<eblk, TB, 0, stream>>>(dst, cnt, E);
    k_dinv<<<nblk, TB, 0, stream>>>(cnt, dinv, N);
    k_scan1<<<nblk, TB, 0, stream>>>(cnt, rowptr, bsum, N);
    k_scan2<<<1, TB, 0, stream>>>(bsum, nblk);
    k_scan3<<<nblk, TB, 0, stream>>>(rowptr, cnt, bsum, N);
    k_scatter<<<eblk, TB, 0, stream>>>(src, dst, rowptr, fill, csr_src, E);
    k_gcount<<<1, 128, 0, stream>>>(batch, invcnt, N);

    // layer 1
    k_gemm128<<<gemm_blocks, TB, 0, stream>>>(x, W1, bufA, N);
    k_gcn_agg<<<agg_blocks, TB, 0, stream>>>(bufA, csr_src, rowptr, cnt, dinv, b1, bufB, N);

    // layer 2
    k_gemm128<<<gemm_blocks, TB, 0, stream>>>(bufB, W2, bufA, N);
    k_gcn_agg<<<agg_blocks, TB, 0, stream>>>(bufA, csr_src, rowptr, cnt, dinv, b2, bufB, N);

    // pool + head
    k_pool3<<<pool_blocks, 128, 0, stream>>>(bufB, batch, invcnt, pooled, N);
    k_fc1<<<128, 64, 0, stream>>>(pooled, fcW1, fcb1, Z);
    k_bn_out<<<1, 256, 0, stream>>>(Z, gamma, beta, fcW3, fcb3, out);
}